// Round 2
// baseline (644.665 us; speedup 1.0000x reference)
//
#include <hip/hip_runtime.h>

// Problem constants (B, L, H, D) = (4, 4096, 8, 64), FACTOR=5
// Inputs/outputs are float32 per the reference (jnp.float32).
#define NB 4
#define LSEQ 4096
#define NH 8
#define ND 64
#define NSAMP 45
#define NTOP 45

typedef float f32x4 __attribute__((ext_vector_type(4)));

// ---------------------------------------------------------------------------
// Kernel 1: M[b,h,l] = max_s(q.k_s) - sum_s(q.k_s)/LSEQ over 45 sampled keys.
// ONE THREAD per (b,h,l), EXACT butterfly-equivalent add tree (bit-identical
// M => selection frozen). Round-7 changes (mapping + scheduling only):
//  * XCD pinning: blockIdx&7 owns (b = xcd>>1, head-half = xcd&1). The K
//    gather working set per XCD is 4096 rows x 4 heads x 256 B = 4 MB =
//    exactly one XCD's L2 -> the 45x re-read stream becomes L2-resident
//    (FETCH_SIZE 667 MB -> compulsory-ish).
//  * Explicit double-buffered K rows + idx prefetch: 16 loads in flight
//    while the previous sample's tree executes (old 68-VGPR allocation had
//    sunk loads into the tree -> latency-serial, VALUBusy 3.2%).
//  * Non-temporal Q loads (via ext_vector_type for the builtin): don't evict
//    the L2 K residency with the one-shot Q stream.
// Occupancy is grid-bound (512 blocks -> 2 waves/SIMD), so VGPRs up to 256
// are free; __launch_bounds__(256,2) caps allocation at 256 (no spill).
// ---------------------------------------------------------------------------
__global__ __launch_bounds__(256, 2) void compute_M_kernel(
        const float* __restrict__ Q,
        const float* __restrict__ K,
        const int* __restrict__ idxS,
        float* __restrict__ Mout) {
    // 512 blocks. xcd-slot = blockIdx&7 -> (b, h-half); slot = blockIdx>>3
    // (0..63) -> l-chunk of 64. Threads: 4 adjacent lanes share l (their 4
    // heads form one contiguous 1 KB K chunk), 64 l per block.
    int xcd  = blockIdx.x & 7;
    int slot = blockIdx.x >> 3;
    int b  = xcd >> 1;
    int hh = xcd & 1;
    int t  = threadIdx.x;
    int h  = (hh << 2) | (t & 3);
    int l  = (slot << 6) | (t >> 2);

    const f32x4* qp = reinterpret_cast<const f32x4*>(
        Q + (((size_t)b * LSEQ + l) * NH + h) * ND);
    f32x4 q4[16];
    #pragma unroll
    for (int i = 0; i < 16; ++i) q4[i] = __builtin_nontemporal_load(qp + i);

    const int* is = idxS + (size_t)l * NSAMP;
    size_t kbh = ((size_t)b * LSEQ * NH + h) * ND;

    float maxv = -INFINITY;
    float sumv = 0.0f;

    auto loadK = [&](f32x4 (&dst)[16], int idx) {
        const f32x4* kp = reinterpret_cast<const f32x4*>(
            K + kbh + (size_t)idx * (NH * ND));
        #pragma unroll
        for (int i = 0; i < 16; ++i) dst[i] = kp[i];
    };

    // EXACT same arithmetic as prior rounds: stage off=32 fused with
    // products, then off=16,8,4,2,1; sequential maxv/sumv updates.
    auto step = [&](const f32x4 (&k4)[16]) {
        float w[32];
        #pragma unroll
        for (int i = 0; i < 8; ++i) {
            f32x4 a = q4[i], bb = k4[i], c = q4[i + 8], d4 = k4[i + 8];
            w[4 * i + 0] = __fadd_rn(__fmul_rn(a.x, bb.x), __fmul_rn(c.x, d4.x));
            w[4 * i + 1] = __fadd_rn(__fmul_rn(a.y, bb.y), __fmul_rn(c.y, d4.y));
            w[4 * i + 2] = __fadd_rn(__fmul_rn(a.z, bb.z), __fmul_rn(c.z, d4.z));
            w[4 * i + 3] = __fadd_rn(__fmul_rn(a.w, bb.w), __fmul_rn(c.w, d4.w));
        }
        #pragma unroll
        for (int off = 16; off; off >>= 1) {
            #pragma unroll
            for (int i = 0; i < off; ++i) w[i] = __fadd_rn(w[i], w[i + off]);
        }
        float p = w[0];
        maxv = fmaxf(maxv, p);
        sumv = __fadd_rn(sumv, p);
    };

    // Software pipeline: 2 samples per iteration, idx fetched one iteration
    // ahead, K rows double-buffered (ka/kb). Sample ORDER s=0..44 preserved.
    f32x4 ka[16], kb[16];
    int j1 = is[1];
    int j2 = is[2];
    loadK(ka, is[0]);

    for (int s = 0; s < NSAMP - 1; s += 2) {
        int j3 = 0, j4 = 0;
        if (s + 3 < NSAMP) j3 = is[s + 3];
        if (s + 4 < NSAMP) j4 = is[s + 4];
        loadK(kb, j1);   // K row for sample s+1 in flight
        step(ka);        // sample s
        loadK(ka, j2);   // K row for sample s+2 in flight
        step(kb);        // sample s+1
        j1 = j3; j2 = j4;
    }
    step(ka);            // sample 44 (loaded at s=42)

    Mout[((size_t)b * NH + h) * LSEQ + l] = maxv - sumv * (1.0f / (float)LSEQ);
}

// ---------------------------------------------------------------------------
// Kernel 2: top-45 per (b,h). UNCHANGED (selection semantics frozen).
// ---------------------------------------------------------------------------
__global__ __launch_bounds__(256) void topk_kernel(
        const float* __restrict__ M, int* __restrict__ Mtop) {
    int bh = blockIdx.x;
    int t = threadIdx.x;
    int wave = t >> 6, lane = t & 63;
    const float* m = M + (size_t)bh * LSEQ;

    float rv[16];
    #pragma unroll
    for (int k = 0; k < 16; ++k) rv[k] = m[t + (k << 8)];

    __shared__ float wv[4];
    __shared__ int   wi[4];
    __shared__ int   winIdx;

    for (int iter = 0; iter < NTOP; ++iter) {
        float bv = -INFINITY; int bi = 0x7fffffff;
        #pragma unroll
        for (int k = 0; k < 16; ++k) {
            float v = rv[k];
            if (v > bv) { bv = v; bi = t + (k << 8); }
        }
        #pragma unroll
        for (int off = 1; off < 64; off <<= 1) {
            float ov = __shfl_xor(bv, off, 64);
            int   oi = __shfl_xor(bi, off, 64);
            if (ov > bv || (ov == bv && oi < bi)) { bv = ov; bi = oi; }
        }
        if (lane == 0) { wv[wave] = bv; wi[wave] = bi; }
        __syncthreads();
        if (t == 0) {
            float cv = wv[0]; int ci = wi[0];
            for (int ww = 1; ww < 4; ++ww) {
                if (wv[ww] > cv || (wv[ww] == cv && wi[ww] < ci)) { cv = wv[ww]; ci = wi[ww]; }
            }
            winIdx = ci;
            Mtop[bh * NTOP + iter] = ci;
        }
        __syncthreads();
        int widx = winIdx;
        #pragma unroll
        for (int k = 0; k < 16; ++k)
            if (widx == t + (k << 8)) rv[k] = -INFINITY;
        __syncthreads();
    }
}

// ---------------------------------------------------------------------------
// Kernel 3a: per-chunk sums of V (16 chunks of 256 rows per (b,h)).
// Grid 512 = (bh,c); 256 thr = 4 row-groups x 64 d. Reads 32 MB once.
// ---------------------------------------------------------------------------
__global__ __launch_bounds__(256) void cumsumA_kernel(
        const float* __restrict__ V, float* __restrict__ chunkSums) {
    int blk = blockIdx.x;
    int c = blk & 15;
    int bh = blk >> 4;
    int h = bh & (NH - 1);
    int b = bh >> 3;
    int g = threadIdx.x >> 6, d = threadIdx.x & 63;

    const size_t rstride = (size_t)NH * ND;   // 512
    size_t vbase = (size_t)b * LSEQ * rstride + (size_t)h * ND + d;

    int l0 = c * 256 + g * 64;
    float s = 0.0f;
    for (int l = l0; l < l0 + 64; ++l) s += V[vbase + (size_t)l * rstride];

    __shared__ float part[4][ND];
    part[g][d] = s;
    __syncthreads();
    if (threadIdx.x < ND)
        chunkSums[(size_t)blk * ND + d] =
            part[0][d] + part[1][d] + part[2][d] + part[3][d];
}

// ---------------------------------------------------------------------------
// Kernel 3b: rescan chunk with exclusive prefix from chunkSums, write out.
// Grid 512 = (bh,c); 256 thr = 4 row-groups x 64 d. Reads 32 MB + writes 32.
// ---------------------------------------------------------------------------
__global__ __launch_bounds__(256) void cumsumC_kernel(
        const float* __restrict__ V, const float* __restrict__ chunkSums,
        float* __restrict__ out) {
    int blk = blockIdx.x;
    int c = blk & 15;
    int bh = blk >> 4;
    int h = bh & (NH - 1);
    int b = bh >> 3;
    int g = threadIdx.x >> 6, d = threadIdx.x & 63;

    const size_t rstride = (size_t)NH * ND;
    size_t vbase = (size_t)b * LSEQ * rstride + (size_t)h * ND + d;

    // prefix over earlier chunks
    float run = 0.0f;
    for (int cc = 0; cc < c; ++cc)
        run += chunkSums[((size_t)bh * 16 + cc) * ND + d];

    // within-chunk group partials
    int l0 = c * 256 + g * 64;
    float s = 0.0f;
    for (int l = l0; l < l0 + 64; ++l) s += V[vbase + (size_t)l * rstride];
    __shared__ float part[4][ND];
    part[g][d] = s;
    __syncthreads();
    for (int gg = 0; gg < g; ++gg) run += part[gg][d];

    size_t obase = (size_t)bh * LSEQ * ND + d;
    for (int l = l0; l < l0 + 64; ++l) {
        run += V[vbase + (size_t)l * rstride];
        out[obase + (size_t)l * ND] = run;
    }
}

// ---------------------------------------------------------------------------
// Kernel 4: per (b,h,u) flash attention, LDS-tiled (body as round 6).
// blockIdx remapped so all 45 u-blocks of one (b,h) land on ONE XCD
// (round-robin heuristic) and share the K/V stream in that XCD's L2.
// ---------------------------------------------------------------------------
#define TJ 64
__global__ __launch_bounds__(256) void attn_rows_kernel(
        const float* __restrict__ Q,
        const float* __restrict__ K,
        const float* __restrict__ V,
        const int* __restrict__ Mtop,
        float* __restrict__ out) {
    int x = blockIdx.x;
    int xcd = x & 7;
    int slot = x >> 3;           // 0..179
    int grp = slot / NTOP;       // 0..3
    int u = slot % NTOP;
    int bh = grp * 8 + xcd;      // all u of this bh share an XCD
    int h = bh & (NH - 1);
    int b = bh >> 3;
    int pos = Mtop[bh * NTOP + u];
    int n = pos + 1;
    int t = threadIdx.x;
    int r = t >> 2, qt = t & 3;

    __shared__ float Ks[TJ][65];
    __shared__ float Vs[TJ][65];
    __shared__ float red[256];

    const size_t rstride = (size_t)NH * ND;   // 512
    size_t base = (size_t)b * LSEQ * rstride + (size_t)h * ND;

    float qreg[16];
    const float* qrow = Q + base + (size_t)pos * rstride + qt * 16;
    #pragma unroll
    for (int i = 0; i < 16; i += 4) {
        float4 v4 = *reinterpret_cast<const float4*>(qrow + i);
        qreg[i] = v4.x; qreg[i + 1] = v4.y; qreg[i + 2] = v4.z; qreg[i + 3] = v4.w;
    }

    float m = -INFINITY, s = 0.0f;
    float o[16];
    #pragma unroll
    for (int dd = 0; dd < 16; ++dd) o[dd] = 0.0f;

    int ntiles = (n + TJ - 1) / TJ;
    for (int tt = 0; tt < ntiles; ++tt) {
        int j0 = tt * TJ;
        __syncthreads();
        #pragma unroll
        for (int i = 0; i < 4; ++i) {
            int u16 = t + i * 256;
            int rr = u16 >> 4, cc = u16 & 15;
            int j = j0 + rr;
            int jc = (j < n) ? j : (n - 1);
            const float* rowk = K + base + (size_t)jc * rstride;
            float4 kv = *reinterpret_cast<const float4*>(rowk + cc * 4);
            Ks[rr][cc * 4 + 0] = kv.x; Ks[rr][cc * 4 + 1] = kv.y;
            Ks[rr][cc * 4 + 2] = kv.z; Ks[rr][cc * 4 + 3] = kv.w;
            const float* rowv = V + base + (size_t)jc * rstride;
            float4 vv = *reinterpret_cast<const float4*>(rowv + cc * 4);
            Vs[rr][cc * 4 + 0] = vv.x; Vs[rr][cc * 4 + 1] = vv.y;
            Vs[rr][cc * 4 + 2] = vv.z; Vs[rr][cc * 4 + 3] = vv.w;
        }
        __syncthreads();

        int j = j0 + r;
        float acc = 0.0f;
        #pragma unroll
        for (int dd = 0; dd < 16; ++dd)
            acc = fmaf(qreg[dd], Ks[r][qt * 16 + dd], acc);
        acc += __shfl_xor(acc, 1, 64);
        acc += __shfl_xor(acc, 2, 64);

        if (j < n) {
            float sc = acc * 0.125f;
            if (sc > m) {
                float alpha = __expf(m - sc);
                s *= alpha;
                #pragma unroll
                for (int dd = 0; dd < 16; ++dd) o[dd] *= alpha;
                m = sc;
            }
            float e = __expf(sc - m);
            s += e;
            #pragma unroll
            for (int dd = 0; dd < 16; ++dd)
                o[dd] = fmaf(e, Vs[r][qt * 16 + dd], o[dd]);
        }
    }
    __syncthreads();

    red[t] = m; __syncthreads();
    for (int sft = 128; sft; sft >>= 1) {
        if (t < sft) red[t] = fmaxf(red[t], red[t + sft]);
        __syncthreads();
    }
    float mstar = red[0]; __syncthreads();
    float a = __expf(m - mstar);

    red[t] = s * a; __syncthreads();
    for (int sft = 128; sft; sft >>= 1) {
        if (t < sft) red[t] += red[t + sft];
        __syncthreads();
    }
    float S = red[0]; __syncthreads();

    float* OB = &Ks[0][0];
    #pragma unroll
    for (int dd = 0; dd < 16; ++dd) OB[t * 16 + dd] = o[dd] * a;
    __syncthreads();

    if (t < ND) {
        int qtt = t >> 4, dd = t & 15;
        float tot = 0.0f;
        for (int k = 0; k < 64; ++k) tot += OB[(4 * k + qtt) * 16 + dd];
        out[((size_t)bh * LSEQ + pos) * ND + t] = tot / S;
    }
}

// ---------------------------------------------------------------------------
extern "C" void kernel_launch(void* const* d_in, const int* in_sizes, int n_in,
                              void* d_out, int out_size, void* d_ws, size_t ws_size,
                              hipStream_t stream) {
    const float* Q = (const float*)d_in[0];
    const float* K = (const float*)d_in[1];
    const float* V = (const float*)d_in[2];
    const int* idxS = (const int*)d_in[3];
    float* out = (float*)d_out;

    // M (fp32, 512 KB) lives in d_out — consumed by topk before cumsum
    // overwrites d_out. ws: Mtop (5760 B) @0, chunkSums (128 KB) @8192.
    float* Mbuf = (float*)d_out;
    int*   Mtop = (int*)d_ws;
    float* chunkSums = (float*)((char*)d_ws + 8192);

    compute_M_kernel<<<NB * NH * LSEQ / 256, 256, 0, stream>>>(Q, K, idxS, Mbuf);
    topk_kernel<<<NB * NH, 256, 0, stream>>>(Mbuf, Mtop);
    cumsumA_kernel<<<NB * NH * 16, 256, 0, stream>>>(V, chunkSums);
    cumsumC_kernel<<<NB * NH * 16, 256, 0, stream>>>(V, chunkSums, out);
    attn_rows_kernel<<<NB * NH * NTOP, 256, 0, stream>>>(Q, K, V, Mtop, out);
}